// Round 2
// baseline (2441.205 us; speedup 1.0000x reference)
//
#include <hip/hip_runtime.h>

typedef unsigned short u16;
typedef __attribute__((ext_vector_type(8))) short bf16x8;
typedef __attribute__((ext_vector_type(4))) float f32x4;

__device__ __forceinline__ u16 f2b(float f) {
    union { unsigned int i; float f; } x; x.f = f;
    unsigned int r = (x.i + 0x7fffu + ((x.i >> 16) & 1u)) >> 16;
    return (u16)r;
}
__device__ __forceinline__ float b2f(u16 u) {
    union { unsigned int i; float f; } x; x.i = ((unsigned int)u) << 16; return x.f;
}

__device__ __forceinline__ void gload16(const u16* g, u16* l) {
    __builtin_amdgcn_global_load_lds(
        (const __attribute__((address_space(1))) void*)g,
        (__attribute__((address_space(3))) void*)l, 16, 0, 0);
}

// ---------------- fp32 -> bf16 weight conversion ----------------
__global__ __launch_bounds__(256) void f2b_k(const float* __restrict__ in,
                                             u16* __restrict__ out, int n4) {
    const int i = blockIdx.x * 256 + threadIdx.x;
    if (i < n4) {
        float4 v = ((const float4*)in)[i];
        ushort4 o = { f2b(v.x), f2b(v.y), f2b(v.z), f2b(v.w) };
        ((ushort4*)out)[i] = o;
    }
}

// ---------------- embedding gather: x[n,d] = embed_W[ids[n], d] ----------------
__global__ __launch_bounds__(256) void embed_k(const int* __restrict__ ids,
                                               const float* __restrict__ E,
                                               float* __restrict__ x) {
    const int n = blockIdx.x, t = threadIdx.x;
    const int id = ids[n];
    float4 e = ((const float4*)(E + (size_t)id * 1024))[t];
    ((float4*)(x + (size_t)n * 1024))[t] = e;
}

// ---------------- static physics: retention/gate per (l,h,i,j), all fp32 ----------------
__global__ __launch_bounds__(256) void physics_k(
        const float* __restrict__ W_LTM, const float* __restrict__ V_T0,
        const float* __restrict__ V_gs, const float* __restrict__ beta_tau,
        const float* __restrict__ beta_gm, const float* __restrict__ C_ch,
        const float* __restrict__ gammaP, const float* __restrict__ alphaP,
        const float* __restrict__ ICthr, float* __restrict__ ret, float* __restrict__ gat) {
    const int idx = blockIdx.x * 256 + threadIdx.x;   // < L*H*4096
    const int lh = idx >> 12;   // l*H + h
    const int l  = lh >> 4;     // H = 16
    const float W    = W_LTM[idx];
    const float veff = V_gs[lh] - V_T0[lh] + W;
    const float sp   = fmaxf(veff, 0.f) + log1pf(expf(-fabsf(veff)));  // softplus
    const float gch  = beta_tau[lh] * sp;
    const float G    = beta_gm[lh] * sp / (1.f + expf(-veff));
    const float sgn  = tanhf(alphaP[l] * (gch - ICthr[l]));
    ret[idx] = expf(-gch / C_ch[lh]);                 // 1 - lam
    gat[idx] = gammaP[lh] * sgn * G;
}

// ---------------- LayerNorm over D=1024, one block per row ----------------
template<bool OUTB>
__global__ __launch_bounds__(256) void ln_rows(const float* __restrict__ X,
                                               const float* __restrict__ g,
                                               const float* __restrict__ bb,
                                               void* __restrict__ OUT) {
    const int n = blockIdx.x, t = threadIdx.x;
    const float4 xv = ((const float4*)(X + (size_t)n * 1024))[t];
    float s  = xv.x + xv.y + xv.z + xv.w;
    float s2 = xv.x * xv.x + xv.y * xv.y + xv.z * xv.z + xv.w * xv.w;
#pragma unroll
    for (int m = 32; m; m >>= 1) { s += __shfl_xor(s, m); s2 += __shfl_xor(s2, m); }
    __shared__ float sh[8];
    if ((t & 63) == 0) { sh[t >> 6] = s; sh[4 + (t >> 6)] = s2; }
    __syncthreads();
    s  = sh[0] + sh[1] + sh[2] + sh[3];
    s2 = sh[4] + sh[5] + sh[6] + sh[7];
    const float mean = s * (1.f / 1024.f);
    const float rstd = rsqrtf(s2 * (1.f / 1024.f) - mean * mean + 1e-5f);
    const int d0 = t * 4;
    const float4 gv = *(const float4*)&g[d0];
    const float4 bv = *(const float4*)&bb[d0];
    float o0 = (xv.x - mean) * rstd * gv.x + bv.x;
    float o1 = (xv.y - mean) * rstd * gv.y + bv.y;
    float o2 = (xv.z - mean) * rstd * gv.z + bv.z;
    float o3 = (xv.w - mean) * rstd * gv.w + bv.w;
    if (OUTB) {
        ushort4 o = { f2b(o0), f2b(o1), f2b(o2), f2b(o3) };
        ((ushort4*)((u16*)OUT + (size_t)n * 1024))[t] = o;
    } else {
        float4 o = { o0, o1, o2, o3 };
        ((float4*)((float*)OUT + (size_t)n * 1024))[t] = o;
    }
}

// ---------------- causal depthwise conv (k=3, left pad 2) + residual, out bf16 ----------------
__global__ __launch_bounds__(256) void conv_k(const float* __restrict__ hln,
                                              const float* __restrict__ w,
                                              const float* __restrict__ cb,
                                              u16* __restrict__ out) {
    const int n = blockIdx.x;
    const int tt = n & 2047;           // T = 2048
    const int d0 = threadIdx.x * 4;
    const float4 c = *(const float4*)&hln[(size_t)n * 1024 + d0];
    float4 m1 = { 0, 0, 0, 0 }, m2 = { 0, 0, 0, 0 };
    if (tt >= 1) m1 = *(const float4*)&hln[(size_t)(n - 1) * 1024 + d0];
    if (tt >= 2) m2 = *(const float4*)&hln[(size_t)(n - 2) * 1024 + d0];
    const float4 w0 = *(const float4*)&w[d0];
    const float4 w1 = *(const float4*)&w[1024 + d0];
    const float4 w2 = *(const float4*)&w[2048 + d0];
    const float4 cv = *(const float4*)&cb[d0];
    float o0 = c.x + m2.x * w0.x + m1.x * w1.x + c.x * w2.x + cv.x;
    float o1 = c.y + m2.y * w0.y + m1.y * w1.y + c.y * w2.y + cv.y;
    float o2 = c.z + m2.z * w0.z + m1.z * w1.z + c.z * w2.z + cv.z;
    float o3 = c.w + m2.w * w0.w + m1.w * w1.w + c.w * w2.w + cv.w;
    ushort4 o = { f2b(o0), f2b(o1), f2b(o2), f2b(o3) };
    *(ushort4*)&out[(size_t)n * 1024 + d0] = o;
}

// ---------------- k head-LN over dk=64, in-place on fp32 qkv, one wave per (n,h) ----------------
__global__ __launch_bounds__(256) void kln_k(float* __restrict__ qkv,
                                             const float* __restrict__ g,
                                             const float* __restrict__ bb) {
    const int row = blockIdx.x * 4 + (threadIdx.x >> 6);
    const int lane = threadIdx.x & 63;
    const int n = row >> 4, h = row & 15;        // H = 16
    float* p = qkv + (size_t)n * 3072 + 1024 + h * 64 + lane;
    const float x = *p;
    float s = x, s2 = x * x;
#pragma unroll
    for (int m = 32; m; m >>= 1) { s += __shfl_xor(s, m); s2 += __shfl_xor(s2, m); }
    const float mean = s * (1.f / 64.f);
    const float rstd = rsqrtf(s2 * (1.f / 64.f) - mean * mean + 1e-5f);
    *p = (x - mean) * rstd * g[lane] + bb[lane];
}

// ---------------- bf16 B^T GEMM, m97 recipe: 128x128 tile, 16x16x32 MFMA ----------------
// C[M,N] = A[M,K] * B[N,K]^T.  A,B bf16; C fp32.  MODE 0: store.  MODE 1: +=.
template<int MODE>
__global__ __launch_bounds__(256, 2) void gemm_bt(const u16* __restrict__ A,
                                                  const u16* __restrict__ Bm,
                                                  float* __restrict__ C,
                                                  int Nn, int K) {
    __shared__ u16 lA[128 * 32];
    __shared__ u16 lB[128 * 32];
    const int t = threadIdx.x;
    const int lane = t & 63, wave = t >> 6;
    const int wm = (wave >> 1) * 64, wn = (wave & 1) * 64;
    const int m0 = blockIdx.y * 128, n0 = blockIdx.x * 128;
    f32x4 acc[4][4] = {};
    const int sr = t >> 2, sc = (t & 3) * 8;           // staging: row, k-chunk
    const u16* Ap = A + (size_t)(m0 + sr) * K + sc;
    const u16* Bp = Bm + (size_t)(n0 + sr) * K + sc;
    u16* lAw = lA + t * 8;
    u16* lBw = lB + t * 8;
    const int fr = lane & 15, fk = (lane >> 4) * 8;
    for (int k0 = 0; k0 < K; k0 += 32) {
        __syncthreads();
        gload16(Ap, lAw);
        gload16(Ap + (size_t)64 * K, lAw + 2048);
        gload16(Bp, lBw);
        gload16(Bp + (size_t)64 * K, lBw + 2048);
        Ap += 32; Bp += 32;
        __syncthreads();
        bf16x8 af[4], bf[4];
#pragma unroll
        for (int i = 0; i < 4; ++i) af[i] = *(const bf16x8*)&lA[(wm + i * 16 + fr) * 32 + fk];
#pragma unroll
        for (int i = 0; i < 4; ++i) bf[i] = *(const bf16x8*)&lB[(wn + i * 16 + fr) * 32 + fk];
#pragma unroll
        for (int i = 0; i < 4; ++i)
#pragma unroll
            for (int j = 0; j < 4; ++j)
                acc[i][j] = __builtin_amdgcn_mfma_f32_16x16x32_bf16(af[i], bf[j], acc[i][j], 0, 0, 0);
    }
    const int col = lane & 15, rw = (lane >> 4) * 4;
#pragma unroll
    for (int i = 0; i < 4; ++i)
#pragma unroll
        for (int j = 0; j < 4; ++j)
#pragma unroll
            for (int r = 0; r < 4; ++r) {
                const int gm = m0 + wm + i * 16 + rw + r;
                const int gn = n0 + wn + j * 16 + col;
                if (MODE == 0) C[(size_t)gm * Nn + gn] = acc[i][j][r];
                else           C[(size_t)gm * Nn + gn] += acc[i][j][r];
            }
}

// ---------------- recurrent scan: F = r*F + g*(v k^T); y = (W+F) q ----------------
// grid: B*H*4 blocks (4 row-groups of 16 per (b,h)); 256 threads: i_local = t>>4, j-quad = t&15
__global__ __launch_bounds__(256) void scan_k(const float* __restrict__ qkv,
                                              const float* __restrict__ ret,
                                              const float* __restrict__ gat,
                                              const float* __restrict__ Wl,
                                              u16* __restrict__ y) {
    const int ig = blockIdx.x & 3;
    const int h  = (blockIdx.x >> 2) & 15;
    const int b  = blockIdx.x >> 6;
    const int il = threadIdx.x >> 4;
    const int jq = threadIdx.x & 15;
    const int i  = ig * 16 + il;
    const int j0 = jq * 4;
    const int base = (h * 64 + i) * 64 + j0;
    const float4 r4 = *(const float4*)&ret[base];
    const float4 g4 = *(const float4*)&gat[base];
    const float4 w4 = *(const float4*)&Wl[base];
    float F0 = 0.f, F1 = 0.f, F2 = 0.f, F3 = 0.f;
    const size_t nrow0 = (size_t)b * 2048;
    const float* pq = qkv + nrow0 * 3072 + h * 64 + j0;
    const float* pk = pq + 1024;
    const float* pv = qkv + nrow0 * 3072 + 2048 + h * 64 + i;
    u16* py = y + nrow0 * 1024 + h * 64 + i;
    float4 qn = *(const float4*)pq;
    float4 kn = *(const float4*)pk;
    float vn = *pv;
    for (int t = 0; t < 2048; ++t) {
        const float4 qc = qn, kc = kn;
        const float vc = vn;
        pq += 3072; pk += 3072; pv += 3072;
        if (t + 1 < 2048) { qn = *(const float4*)pq; kn = *(const float4*)pk; vn = *pv; }
        F0 = r4.x * F0 + (g4.x * vc) * kc.x;
        F1 = r4.y * F1 + (g4.y * vc) * kc.y;
        F2 = r4.z * F2 + (g4.z * vc) * kc.z;
        F3 = r4.w * F3 + (g4.w * vc) * kc.w;
        float p = (w4.x + F0) * qc.x + (w4.y + F1) * qc.y + (w4.z + F2) * qc.z + (w4.w + F3) * qc.w;
        p += __shfl_xor(p, 1);
        p += __shfl_xor(p, 2);
        p += __shfl_xor(p, 4);
        p += __shfl_xor(p, 8);
        if (jq == 0) *py = f2b(p);
        py += 1024;
    }
}

extern "C" void kernel_launch(void* const* d_in, const int* in_sizes, int n_in,
                              void* d_out, int out_size, void* d_ws, size_t ws_size,
                              hipStream_t stream) {
    constexpr int Bz = 4, T = 2048, Dd = 1024, Hh = 16, Vv = 8192, Ll = 2;
    constexpr int Nn = Bz * T;   // 8192 tokens
    const int*   ids      = (const int*)d_in[0];
    // d_in[1] = state_quant_bits = 16 -> quantization branch never taken
    const float* embed_W  = (const float*)d_in[2];
    const float* conv_w   = (const float*)d_in[3];
    const float* conv_b   = (const float*)d_in[4];
    const float* Wqkv     = (const float*)d_in[5];
    const float* Wo       = (const float*)d_in[6];
    const float* W_LTM    = (const float*)d_in[7];
    const float* V_T0     = (const float*)d_in[8];
    const float* V_gs     = (const float*)d_in[9];
    const float* beta_tau = (const float*)d_in[10];
    const float* beta_gm  = (const float*)d_in[11];
    const float* C_ch     = (const float*)d_in[12];
    const float* gammaP   = (const float*)d_in[13];
    const float* alphaP   = (const float*)d_in[14];
    const float* ICthr    = (const float*)d_in[15];
    const float* ln1_g    = (const float*)d_in[16];
    const float* ln1_b    = (const float*)d_in[17];
    const float* lnk_g    = (const float*)d_in[18];
    const float* lnk_b    = (const float*)d_in[19];
    const float* lnf_g    = (const float*)d_in[20];
    const float* lnf_b    = (const float*)d_in[21];
    const float* head_W   = (const float*)d_in[22];

    // workspace carve (~219 MB)
    float* x    = (float*)d_ws;                                  // fp32 N*D
    float* qkvF = x + (size_t)Nn * Dd;                           // fp32 N*3D
    float* ret  = qkvF + (size_t)Nn * 3 * Dd;                    // fp32 L*H*4096
    float* gat  = ret + (size_t)Ll * Hh * 4096;
    float* hln  = gat + (size_t)Ll * Hh * 4096;                  // fp32 N*D
    u16*  yb    = (u16*)hln;                                     // bf16 N*D (aliases hln; disjoint lifetime)
    u16*  xf    = yb + (size_t)Nn * Dd;                          // bf16 N*D (fits in hln's 2nd half)
    u16*  hb    = (u16*)(hln + (size_t)Nn * Dd);                 // bf16 N*D
    u16*  wq_b  = hb + (size_t)Nn * Dd;                          // bf16 L*3D*D
    u16*  wo_b  = wq_b + (size_t)Ll * 3 * Dd * Dd;               // bf16 L*D*D
    u16*  wh_b  = wo_b + (size_t)Ll * Dd * Dd;                   // bf16 V*D

    // weight conversions
    f2b_k<<<(Ll * 3 * Dd * Dd / 4 + 255) / 256, 256, 0, stream>>>(Wqkv, wq_b, Ll * 3 * Dd * Dd / 4);
    f2b_k<<<(Ll * Dd * Dd / 4 + 255) / 256, 256, 0, stream>>>(Wo, wo_b, Ll * Dd * Dd / 4);
    f2b_k<<<(Vv * Dd / 4 + 255) / 256, 256, 0, stream>>>(head_W, wh_b, Vv * Dd / 4);

    embed_k<<<Nn, 256, 0, stream>>>(ids, embed_W, x);
    physics_k<<<(Ll * Hh * 4096) / 256, 256, 0, stream>>>(W_LTM, V_T0, V_gs, beta_tau,
                                                          beta_gm, C_ch, gammaP, alphaP,
                                                          ICthr, ret, gat);
    for (int l = 0; l < Ll; ++l) {
        ln_rows<false><<<Nn, 256, 0, stream>>>(x, ln1_g + l * Dd, ln1_b + l * Dd, hln);
        conv_k<<<Nn, 256, 0, stream>>>(hln, conv_w + l * 3 * Dd, conv_b + l * Dd, hb);
        gemm_bt<0><<<dim3(3 * Dd / 128, Nn / 128), 256, 0, stream>>>(
            hb, wq_b + (size_t)l * 3 * Dd * Dd, qkvF, 3 * Dd, Dd);
        kln_k<<<Nn * Hh / 4, 256, 0, stream>>>(qkvF, lnk_g + l * 64, lnk_b + l * 64);
        scan_k<<<Bz * Hh * 4, 256, 0, stream>>>(qkvF, ret + (size_t)l * Hh * 4096,
                                                gat + (size_t)l * Hh * 4096,
                                                W_LTM + (size_t)l * Hh * 4096, yb);
        gemm_bt<1><<<dim3(Dd / 128, Nn / 128), 256, 0, stream>>>(
            yb, wo_b + (size_t)l * Dd * Dd, x, Dd, Dd);
    }
    ln_rows<true><<<Nn, 256, 0, stream>>>(x, lnf_g, lnf_b, xf);
    gemm_bt<0><<<dim3(Vv / 128, Nn / 128), 256, 0, stream>>>(xf, wh_b, (float*)d_out, Vv, Dd);
}

// Round 3
// 1374.123 us; speedup vs baseline: 1.7766x; 1.7766x over previous
//
#include <hip/hip_runtime.h>

typedef unsigned short u16;
typedef __attribute__((ext_vector_type(8))) short bf16x8;
typedef __attribute__((ext_vector_type(4))) float f32x4;

__device__ __forceinline__ u16 f2b(float f) {
    union { unsigned int i; float f; } x; x.f = f;
    unsigned int r = (x.i + 0x7fffu + ((x.i >> 16) & 1u)) >> 16;
    return (u16)r;
}

__device__ __forceinline__ void gload16(const u16* g, u16* l) {
    __builtin_amdgcn_global_load_lds(
        (const __attribute__((address_space(1))) void*)g,
        (__attribute__((address_space(3))) void*)l, 16, 0, 0);
}

// ---------------- fp32 -> bf16 weight conversion ----------------
__global__ __launch_bounds__(256) void f2b_k(const float* __restrict__ in,
                                             u16* __restrict__ out, int n4) {
    const int i = blockIdx.x * 256 + threadIdx.x;
    if (i < n4) {
        float4 v = ((const float4*)in)[i];
        ushort4 o = { f2b(v.x), f2b(v.y), f2b(v.z), f2b(v.w) };
        ((ushort4*)out)[i] = o;
    }
}

// ---------------- embedding gather ----------------
__global__ __launch_bounds__(256) void embed_k(const int* __restrict__ ids,
                                               const float* __restrict__ E,
                                               float* __restrict__ x) {
    const int n = blockIdx.x, t = threadIdx.x;
    const int id = ids[n];
    float4 e = ((const float4*)(E + (size_t)id * 1024))[t];
    ((float4*)(x + (size_t)n * 1024))[t] = e;
}

// ---------------- static physics: retention/gate/r^128 per (l,h,i,j) ----------------
__global__ __launch_bounds__(256) void physics_k(
        const float* __restrict__ W_LTM, const float* __restrict__ V_T0,
        const float* __restrict__ V_gs, const float* __restrict__ beta_tau,
        const float* __restrict__ beta_gm, const float* __restrict__ C_ch,
        const float* __restrict__ gammaP, const float* __restrict__ alphaP,
        const float* __restrict__ ICthr, float* __restrict__ ret,
        float* __restrict__ gat, float* __restrict__ rp) {
    const int idx = blockIdx.x * 256 + threadIdx.x;   // < L*H*4096
    const int lh = idx >> 12;   // l*H + h
    const int l  = lh >> 4;     // H = 16
    const float W    = W_LTM[idx];
    const float veff = V_gs[lh] - V_T0[lh] + W;
    const float sp   = fmaxf(veff, 0.f) + log1pf(expf(-fabsf(veff)));  // softplus
    const float gch  = beta_tau[lh] * sp;
    const float G    = beta_gm[lh] * sp / (1.f + expf(-veff));
    const float sgn  = tanhf(alphaP[l] * (gch - ICthr[l]));
    const float e1   = gch / C_ch[lh];
    ret[idx] = expf(-e1);            // r = 1 - lam
    rp[idx]  = expf(-128.f * e1);    // r^128 (chunk decay), computed exactly
    gat[idx] = gammaP[lh] * sgn * G;
}

// ---------------- LayerNorm over D=1024, one block per row ----------------
template<bool OUTB>
__global__ __launch_bounds__(256) void ln_rows(const float* __restrict__ X,
                                               const float* __restrict__ g,
                                               const float* __restrict__ bb,
                                               void* __restrict__ OUT) {
    const int n = blockIdx.x, t = threadIdx.x;
    const float4 xv = ((const float4*)(X + (size_t)n * 1024))[t];
    float s  = xv.x + xv.y + xv.z + xv.w;
    float s2 = xv.x * xv.x + xv.y * xv.y + xv.z * xv.z + xv.w * xv.w;
#pragma unroll
    for (int m = 32; m; m >>= 1) { s += __shfl_xor(s, m); s2 += __shfl_xor(s2, m); }
    __shared__ float sh[8];
    if ((t & 63) == 0) { sh[t >> 6] = s; sh[4 + (t >> 6)] = s2; }
    __syncthreads();
    s  = sh[0] + sh[1] + sh[2] + sh[3];
    s2 = sh[4] + sh[5] + sh[6] + sh[7];
    const float mean = s * (1.f / 1024.f);
    const float rstd = rsqrtf(s2 * (1.f / 1024.f) - mean * mean + 1e-5f);
    const int d0 = t * 4;
    const float4 gv = *(const float4*)&g[d0];
    const float4 bv = *(const float4*)&bb[d0];
    float o0 = (xv.x - mean) * rstd * gv.x + bv.x;
    float o1 = (xv.y - mean) * rstd * gv.y + bv.y;
    float o2 = (xv.z - mean) * rstd * gv.z + bv.z;
    float o3 = (xv.w - mean) * rstd * gv.w + bv.w;
    if (OUTB) {
        ushort4 o = { f2b(o0), f2b(o1), f2b(o2), f2b(o3) };
        ((ushort4*)((u16*)OUT + (size_t)n * 1024))[t] = o;
    } else {
        float4 o = { o0, o1, o2, o3 };
        ((float4*)((float*)OUT + (size_t)n * 1024))[t] = o;
    }
}

// ---------------- causal depthwise conv (k=3, left pad 2) + residual, out bf16 ----------------
__global__ __launch_bounds__(256) void conv_k(const float* __restrict__ hln,
                                              const float* __restrict__ w,
                                              const float* __restrict__ cb,
                                              u16* __restrict__ out) {
    const int n = blockIdx.x;
    const int tt = n & 2047;           // T = 2048
    const int d0 = threadIdx.x * 4;
    const float4 c = *(const float4*)&hln[(size_t)n * 1024 + d0];
    float4 m1 = { 0, 0, 0, 0 }, m2 = { 0, 0, 0, 0 };
    if (tt >= 1) m1 = *(const float4*)&hln[(size_t)(n - 1) * 1024 + d0];
    if (tt >= 2) m2 = *(const float4*)&hln[(size_t)(n - 2) * 1024 + d0];
    const float4 w0 = *(const float4*)&w[d0];
    const float4 w1 = *(const float4*)&w[1024 + d0];
    const float4 w2 = *(const float4*)&w[2048 + d0];
    const float4 cv = *(const float4*)&cb[d0];
    float o0 = c.x + m2.x * w0.x + m1.x * w1.x + c.x * w2.x + cv.x;
    float o1 = c.y + m2.y * w0.y + m1.y * w1.y + c.y * w2.y + cv.y;
    float o2 = c.z + m2.z * w0.z + m1.z * w1.z + c.z * w2.z + cv.z;
    float o3 = c.w + m2.w * w0.w + m1.w * w1.w + c.w * w2.w + cv.w;
    ushort4 o = { f2b(o0), f2b(o1), f2b(o2), f2b(o3) };
    *(ushort4*)&out[(size_t)n * 1024 + d0] = o;
}

// ---------------- k head-LN over dk=64, in-place on fp32 qkv ----------------
__global__ __launch_bounds__(256) void kln_k(float* __restrict__ qkv,
                                             const float* __restrict__ g,
                                             const float* __restrict__ bb) {
    const int row = blockIdx.x * 4 + (threadIdx.x >> 6);
    const int lane = threadIdx.x & 63;
    const int n = row >> 4, h = row & 15;        // H = 16
    float* p = qkv + (size_t)n * 3072 + 1024 + h * 64 + lane;
    const float x = *p;
    float s = x, s2 = x * x;
#pragma unroll
    for (int m = 32; m; m >>= 1) { s += __shfl_xor(s, m); s2 += __shfl_xor(s2, m); }
    const float mean = s * (1.f / 64.f);
    const float rstd = rsqrtf(s2 * (1.f / 64.f) - mean * mean + 1e-5f);
    *p = (x - mean) * rstd * g[lane] + bb[lane];
}

// ---------------- bf16 B^T GEMM, m97 recipe ----------------
template<int MODE>
__global__ __launch_bounds__(256, 2) void gemm_bt(const u16* __restrict__ A,
                                                  const u16* __restrict__ Bm,
                                                  float* __restrict__ C,
                                                  int Nn, int K) {
    __shared__ u16 lA[128 * 32];
    __shared__ u16 lB[128 * 32];
    const int t = threadIdx.x;
    const int lane = t & 63, wave = t >> 6;
    const int wm = (wave >> 1) * 64, wn = (wave & 1) * 64;
    const int m0 = blockIdx.y * 128, n0 = blockIdx.x * 128;
    f32x4 acc[4][4] = {};
    const int sr = t >> 2, sc = (t & 3) * 8;
    const u16* Ap = A + (size_t)(m0 + sr) * K + sc;
    const u16* Bp = Bm + (size_t)(n0 + sr) * K + sc;
    u16* lAw = lA + t * 8;
    u16* lBw = lB + t * 8;
    const int fr = lane & 15, fk = (lane >> 4) * 8;
    for (int k0 = 0; k0 < K; k0 += 32) {
        __syncthreads();
        gload16(Ap, lAw);
        gload16(Ap + (size_t)64 * K, lAw + 2048);
        gload16(Bp, lBw);
        gload16(Bp + (size_t)64 * K, lBw + 2048);
        Ap += 32; Bp += 32;
        __syncthreads();
        bf16x8 af[4], bf[4];
#pragma unroll
        for (int i = 0; i < 4; ++i) af[i] = *(const bf16x8*)&lA[(wm + i * 16 + fr) * 32 + fk];
#pragma unroll
        for (int i = 0; i < 4; ++i) bf[i] = *(const bf16x8*)&lB[(wn + i * 16 + fr) * 32 + fk];
#pragma unroll
        for (int i = 0; i < 4; ++i)
#pragma unroll
            for (int j = 0; j < 4; ++j)
                acc[i][j] = __builtin_amdgcn_mfma_f32_16x16x32_bf16(af[i], bf[j], acc[i][j], 0, 0, 0);
    }
    const int col = lane & 15, rw = (lane >> 4) * 4;
#pragma unroll
    for (int i = 0; i < 4; ++i)
#pragma unroll
        for (int j = 0; j < 4; ++j)
#pragma unroll
            for (int r = 0; r < 4; ++r) {
                const int gm = m0 + wm + i * 16 + rw + r;
                const int gn = n0 + wn + j * 16 + col;
                if (MODE == 0) C[(size_t)gm * Nn + gn] = acc[i][j][r];
                else           C[(size_t)gm * Nn + gn] += acc[i][j][r];
            }
}

// ============== chunked linear scan: F_t = r*F_{t-1} + g*(v_t k_t^T) ==============
// 16 chunks of 128 steps. Block decode: ig=bid&3, c=(bid>>2)&15, h=(bid>>6)&15, b=bid>>10.
// Threads: il = t>>4 (16 i's), jq = t&15 (j0 = jq*4).

// Pass A: chunk-local final state (zero init), k/v only.
__global__ __launch_bounds__(256) void scanA_k(const float* __restrict__ qkv,
                                               const float* __restrict__ ret,
                                               const float* __restrict__ gat,
                                               float* __restrict__ Floc) {
    const int bid = blockIdx.x;
    const int ig = bid & 3, c = (bid >> 2) & 15, h = (bid >> 6) & 15, b = bid >> 10;
    const int il = threadIdx.x >> 4, jq = threadIdx.x & 15;
    const int i = ig * 16 + il, j0 = jq * 4;
    const int base = (h * 64 + i) * 64 + j0;
    const float4 r4 = *(const float4*)&ret[base];
    const float4 g4 = *(const float4*)&gat[base];
    float F0 = 0.f, F1 = 0.f, F2 = 0.f, F3 = 0.f;
    const size_t nrow0 = (size_t)b * 2048 + (size_t)c * 128;
    const float* pk = qkv + nrow0 * 3072 + 1024 + h * 64 + j0;
    const float* pv = qkv + nrow0 * 3072 + 2048 + h * 64 + i;
    float4 kn = *(const float4*)pk;
    float vn = *pv;
    for (int t = 0; t < 128; ++t) {
        const float4 kc = kn; const float vc = vn;
        pk += 3072; pv += 3072;
        if (t + 1 < 128) { kn = *(const float4*)pk; vn = *pv; }
        F0 = r4.x * F0 + (g4.x * vc) * kc.x;
        F1 = r4.y * F1 + (g4.y * vc) * kc.y;
        F2 = r4.z * F2 + (g4.z * vc) * kc.z;
        F3 = r4.w * F3 + (g4.w * vc) * kc.w;
    }
    float4 Fo = { F0, F1, F2, F3 };
    *(float4*)&Floc[((size_t)((b * 16 + h) * 16 + c)) * 4096 + i * 64 + j0] = Fo;
}

// Pass B: prefix across chunks. Fin[c] = state entering chunk c.
__global__ __launch_bounds__(256) void scanB_k(const float* __restrict__ rp,
                                               const float* __restrict__ Floc,
                                               float* __restrict__ Fin) {
    const int idx = blockIdx.x * 256 + threadIdx.x;   // < B*H*4096 = 262144
    const int e = idx & 4095;
    const int bh = idx >> 12;
    const int h = bh & 15;
    const float rpv = rp[h * 4096 + e];
    float F = 0.f;
#pragma unroll
    for (int c = 0; c < 16; ++c) {
        const size_t o = ((size_t)bh * 16 + c) * 4096 + e;
        Fin[o] = F;
        F = rpv * F + Floc[o];
    }
}

// Pass C: outputs, seeded with Fin.
__global__ __launch_bounds__(256) void scanC_k(const float* __restrict__ qkv,
                                               const float* __restrict__ ret,
                                               const float* __restrict__ gat,
                                               const float* __restrict__ Wl,
                                               const float* __restrict__ Fin,
                                               u16* __restrict__ y) {
    const int bid = blockIdx.x;
    const int ig = bid & 3, c = (bid >> 2) & 15, h = (bid >> 6) & 15, b = bid >> 10;
    const int il = threadIdx.x >> 4, jq = threadIdx.x & 15;
    const int i = ig * 16 + il, j0 = jq * 4;
    const int base = (h * 64 + i) * 64 + j0;
    const float4 r4 = *(const float4*)&ret[base];
    const float4 g4 = *(const float4*)&gat[base];
    const float4 w4 = *(const float4*)&Wl[base];
    const float4 Fi = *(const float4*)&Fin[((size_t)((b * 16 + h) * 16 + c)) * 4096 + i * 64 + j0];
    float F0 = Fi.x, F1 = Fi.y, F2 = Fi.z, F3 = Fi.w;
    const size_t nrow0 = (size_t)b * 2048 + (size_t)c * 128;
    const float* pq = qkv + nrow0 * 3072 + h * 64 + j0;
    const float* pk = pq + 1024;
    const float* pv = qkv + nrow0 * 3072 + 2048 + h * 64 + i;
    u16* py = y + nrow0 * 1024 + h * 64 + i;
    float4 qn = *(const float4*)pq;
    float4 kn = *(const float4*)pk;
    float vn = *pv;
    for (int t = 0; t < 128; ++t) {
        const float4 qc = qn, kc = kn;
        const float vc = vn;
        pq += 3072; pk += 3072; pv += 3072;
        if (t + 1 < 128) { qn = *(const float4*)pq; kn = *(const float4*)pk; vn = *pv; }
        F0 = r4.x * F0 + (g4.x * vc) * kc.x;
        F1 = r4.y * F1 + (g4.y * vc) * kc.y;
        F2 = r4.z * F2 + (g4.z * vc) * kc.z;
        F3 = r4.w * F3 + (g4.w * vc) * kc.w;
        float p = (w4.x + F0) * qc.x + (w4.y + F1) * qc.y + (w4.z + F2) * qc.z + (w4.w + F3) * qc.w;
        p += __shfl_xor(p, 1);
        p += __shfl_xor(p, 2);
        p += __shfl_xor(p, 4);
        p += __shfl_xor(p, 8);
        if (jq == 0) *py = f2b(p);
        py += 1024;
    }
}

extern "C" void kernel_launch(void* const* d_in, const int* in_sizes, int n_in,
                              void* d_out, int out_size, void* d_ws, size_t ws_size,
                              hipStream_t stream) {
    constexpr int Bz = 4, T = 2048, Dd = 1024, Hh = 16, Vv = 8192, Ll = 2;
    constexpr int Nn = Bz * T;   // 8192 tokens
    const int*   ids      = (const int*)d_in[0];
    const float* embed_W  = (const float*)d_in[2];
    const float* conv_w   = (const float*)d_in[3];
    const float* conv_b   = (const float*)d_in[4];
    const float* Wqkv     = (const float*)d_in[5];
    const float* Wo       = (const float*)d_in[6];
    const float* W_LTM    = (const float*)d_in[7];
    const float* V_T0     = (const float*)d_in[8];
    const float* V_gs     = (const float*)d_in[9];
    const float* beta_tau = (const float*)d_in[10];
    const float* beta_gm  = (const float*)d_in[11];
    const float* C_ch     = (const float*)d_in[12];
    const float* gammaP   = (const float*)d_in[13];
    const float* alphaP   = (const float*)d_in[14];
    const float* ICthr    = (const float*)d_in[15];
    const float* ln1_g    = (const float*)d_in[16];
    const float* ln1_b    = (const float*)d_in[17];
    const float* lnk_g    = (const float*)d_in[18];
    const float* lnk_b    = (const float*)d_in[19];
    const float* lnf_g    = (const float*)d_in[20];
    const float* lnf_b    = (const float*)d_in[21];
    const float* head_W   = (const float*)d_in[22];

    // workspace carve (~220 MB)
    float* x    = (float*)d_ws;                                  // fp32 N*D
    float* qkvF = x + (size_t)Nn * Dd;                           // fp32 N*3D
    float* ret  = qkvF + (size_t)Nn * 3 * Dd;                    // fp32 L*H*4096
    float* gat  = ret + (size_t)Ll * Hh * 4096;
    float* rp   = gat + (size_t)Ll * Hh * 4096;                  // fp32 L*H*4096 (r^128)
    float* hln  = rp + (size_t)Ll * Hh * 4096;                   // fp32 N*D
    u16*  yb    = (u16*)hln;                                     // bf16 N*D  (aliases hln 1st half)
    u16*  xf    = yb + (size_t)Nn * Dd;                          // bf16 N*D  (aliases hln 2nd half)
    float* Fin  = (float*)xf;                                    // fp32 B*H*16*4096 = same bytes as xf
    u16*  hb    = (u16*)(hln + (size_t)Nn * Dd);                 // bf16 N*D
    float* Floc = (float*)hb;                                    // fp32 B*H*16*4096 = same bytes as hb
    u16*  wq_b  = hb + (size_t)Nn * Dd;                          // bf16 L*3D*D
    u16*  wo_b  = wq_b + (size_t)Ll * 3 * Dd * Dd;               // bf16 L*D*D
    u16*  wh_b  = wo_b + (size_t)Ll * Dd * Dd;                   // bf16 V*D

    // weight conversions
    f2b_k<<<(Ll * 3 * Dd * Dd / 4 + 255) / 256, 256, 0, stream>>>(Wqkv, wq_b, Ll * 3 * Dd * Dd / 4);
    f2b_k<<<(Ll * Dd * Dd / 4 + 255) / 256, 256, 0, stream>>>(Wo, wo_b, Ll * Dd * Dd / 4);
    f2b_k<<<(Vv * Dd / 4 + 255) / 256, 256, 0, stream>>>(head_W, wh_b, Vv * Dd / 4);

    embed_k<<<Nn, 256, 0, stream>>>(ids, embed_W, x);
    physics_k<<<(Ll * Hh * 4096) / 256, 256, 0, stream>>>(W_LTM, V_T0, V_gs, beta_tau,
                                                          beta_gm, C_ch, gammaP, alphaP,
                                                          ICthr, ret, gat, rp);
    for (int l = 0; l < Ll; ++l) {
        const float* retl = ret + (size_t)l * Hh * 4096;
        const float* gatl = gat + (size_t)l * Hh * 4096;
        ln_rows<false><<<Nn, 256, 0, stream>>>(x, ln1_g + l * Dd, ln1_b + l * Dd, hln);
        conv_k<<<Nn, 256, 0, stream>>>(hln, conv_w + l * 3 * Dd, conv_b + l * Dd, hb);
        gemm_bt<0><<<dim3(3 * Dd / 128, Nn / 128), 256, 0, stream>>>(
            hb, wq_b + (size_t)l * 3 * Dd * Dd, qkvF, 3 * Dd, Dd);
        kln_k<<<Nn * Hh / 4, 256, 0, stream>>>(qkvF, lnk_g + l * 64, lnk_b + l * 64);
        scanA_k<<<Bz * Hh * 16 * 4, 256, 0, stream>>>(qkvF, retl, gatl, Floc);
        scanB_k<<<Bz * Hh * 4096 / 256, 256, 0, stream>>>(rp + (size_t)l * Hh * 4096, Floc, Fin);
        scanC_k<<<Bz * Hh * 16 * 4, 256, 0, stream>>>(qkvF, retl, gatl,
                                                      W_LTM + (size_t)l * Hh * 4096, Fin, yb);
        gemm_bt<1><<<dim3(Dd / 128, Nn / 128), 256, 0, stream>>>(
            yb, wo_b + (size_t)l * Dd * Dd, x, Dd, Dd);
    }
    ln_rows<true><<<Nn, 256, 0, stream>>>(x, lnf_g, lnf_b, xf);
    gemm_bt<0><<<dim3(Vv / 128, Nn / 128), 256, 0, stream>>>(xf, wh_b, (float*)d_out, Vv, Dd);
}